// Round 14
// baseline (472.114 us; speedup 1.0000x reference)
//
#include <hip/hip_runtime.h>

#define EPS 1e-5f
#define CAP 64           // ELL row capacity (Poisson(16) tail @64 ~ 1e-22)
#define NXCD 8
#define ECHUNK 2048      // edges per chunk; 8 blocks (one per XCD) per chunk

typedef __attribute__((ext_vector_type(8))) short short8v;
typedef __attribute__((ext_vector_type(4))) float f32x4;

__device__ __forceinline__ unsigned short f2bf(float f) {
    union { float f; unsigned int u; } v; v.f = f;
    unsigned int r = v.u + 0x7fffu + ((v.u >> 16) & 1u);
    return (unsigned short)(r >> 16);
}
__device__ __forceinline__ float bf2f(unsigned short h) {
    union { unsigned int u; float f; } v; v.u = ((unsigned int)h) << 16;
    return v.f;
}

// ---------------- ELL build: XCD-local by dst-range filter; nt loads for streaming src/dst ----------------
__global__ __launch_bounds__(256) void ell_fill(const int* __restrict__ src, const int* __restrict__ dst,
                                                int* __restrict__ cnt, int* __restrict__ ell,
                                                int E, int nper) {
    const int xcd = blockIdx.x & (NXCD - 1);
    const int chunk = blockIdx.x >> 3;
    const int dLo = xcd * nper;
    const int dHi = dLo + nper;
    const int base = chunk * ECHUNK;
#pragma unroll
    for (int it = 0; it < ECHUNK / 256; ++it) {
        int i = base + it * 256 + threadIdx.x;
        if (i < E) {
            int d = __builtin_nontemporal_load(dst + i);
            if (d >= dLo && d < dHi) {
                int s = __builtin_nontemporal_load(src + i);
                int pos = atomicAdd(&cnt[d], 1);
                if (pos < CAP) ell[((size_t)d << 6) + pos] = s;
            }
        }
    }
}

// ---------------- fused prep: cast_x (42->48, dis-prescale, bf16) + 4x split_w ----------------
__global__ __launch_bounds__(256) void prep(const float* __restrict__ x, const int* __restrict__ cnt,
                                            unsigned short* __restrict__ xs1,
                                            const float* __restrict__ W1, unsigned short* __restrict__ w1h,
                                            unsigned short* __restrict__ w1l,
                                            const float* __restrict__ W2, unsigned short* __restrict__ w2h,
                                            unsigned short* __restrict__ w2l,
                                            const float* __restrict__ W3, unsigned short* __restrict__ w3h,
                                            unsigned short* __restrict__ w3l,
                                            const float* __restrict__ W4, unsigned short* __restrict__ w4h,
                                            unsigned short* __restrict__ w4l,
                                            int n, int nbx) {
    int bi = blockIdx.x;
    if (bi < nbx) {                       // cast_x: xs1 = bf16(dis * x), pad 42->48
        int gid = bi * 256 + threadIdx.x;
        int nd = gid / 48, c = gid - nd * 48;
        if (nd < n) {
            float v = 0.0f;
            if (c < 42) v = x[(size_t)nd * 42 + c] * rsqrtf((float)cnt[nd] + 1.0f);
            xs1[(size_t)nd * 48 + c] = f2bf(v);
        }
        return;
    }
    bi -= nbx;
    if (bi < 32) {                        // split W1: [42][128] -> T hi/lo [128][64] (k-pad 64)
        int i = bi * 256 + threadIdx.x;
        int c = i >> 6, k = i & 63;
        float w = (k < 42) ? W1[(size_t)k * 128 + c] : 0.0f;
        unsigned short h = f2bf(w);
        w1h[i] = h; w1l[i] = f2bf(w - bf2f(h));
        return;
    }
    bi -= 32;
    if (bi < 128) {                       // split W2: [128][256] -> T hi/lo [256][128]
        int i = bi * 256 + threadIdx.x;
        int c = i >> 7, k = i & 127;
        float w = W2[(size_t)k * 256 + c];
        unsigned short h = f2bf(w);
        w2h[i] = h; w2l[i] = f2bf(w - bf2f(h));
        return;
    }
    bi -= 128;
    if (bi < 128) {                       // split W3: [256][128] -> T hi/lo [128][256]
        int i = bi * 256 + threadIdx.x;
        int c = i >> 8, k = i & 255;
        float w = W3[(size_t)k * 128 + c];
        unsigned short h = f2bf(w);
        w3h[i] = h; w3l[i] = f2bf(w - bf2f(h));
        return;
    }
    bi -= 128;
    {                                     // split W4: [128][64] -> T hi/lo [64][128]
        int i = bi * 256 + threadIdx.x;
        int c = i >> 7, k = i & 127;
        float w = W4[(size_t)k * 64 + c];
        unsigned short h = f2bf(w);
        w4h[i] = h; w4l[i] = f2bf(w - bf2f(h));
        return;
    }
}

// ---------------- bf16 prescaled aggregation (ELL): out[nd] = dis[nd]*(x[nd] + sum x[src]) ----------------
// FUSE 0: plain ; FUSE 1: relu(agg + (b*s+t)).  Output bf16. 8 elems (16B) per lane.
template<int D, int FUSE>
__global__ __launch_bounds__(256) void agg_bf(const unsigned short* __restrict__ x,
                                              const int* __restrict__ cnt, const int* __restrict__ ell,
                                              const float* __restrict__ b, const float* __restrict__ g,
                                              const float* __restrict__ be, const float* __restrict__ rm,
                                              const float* __restrict__ rv,
                                              unsigned short* __restrict__ out, int n) {
    constexpr int CPE = D / 8;
    int gid = blockIdx.x * 256 + threadIdx.x;
    int nd = gid / CPE, c = gid - nd * CPE;
    if (nd >= n) return;
    const size_t boff = (size_t)nd * D + c * 8;

    float acc[8];
    {
        short8v v = *reinterpret_cast<const short8v*>(x + boff);
#pragma unroll
        for (int j = 0; j < 8; ++j) acc[j] = bf2f((unsigned short)v[j]);
    }
    const int cv = cnt[nd];
    const int deg = (cv < CAP) ? cv : CAP;
    const float dn = rsqrtf((float)cv + 1.0f);
    const int* row = ell + ((size_t)nd << 6);
    int i = 0;
    for (; i + 2 <= deg; i += 2) {
        int s0 = row[i], s1 = row[i + 1];
        short8v v0 = *reinterpret_cast<const short8v*>(x + (size_t)s0 * D + c * 8);
        short8v v1 = *reinterpret_cast<const short8v*>(x + (size_t)s1 * D + c * 8);
#pragma unroll
        for (int j = 0; j < 8; ++j) acc[j] += bf2f((unsigned short)v0[j]) + bf2f((unsigned short)v1[j]);
    }
    if (i < deg) {
        int s0 = row[i];
        short8v v = *reinterpret_cast<const short8v*>(x + (size_t)s0 * D + c * 8);
#pragma unroll
        for (int j = 0; j < 8; ++j) acc[j] += bf2f((unsigned short)v[j]);
    }

#pragma unroll
    for (int j = 0; j < 8; ++j) acc[j] *= dn;

    if (FUSE == 1) {
#pragma unroll
        for (int j = 0; j < 8; ++j) {
            int col = c * 8 + j;
            float sv = g[col] * rsqrtf(rv[col] + EPS);
            float bb = b[col] * sv + (be[col] - rm[col] * sv);
            acc[j] = fmaxf(acc[j] + bb, 0.0f);
        }
    }

    uint4 pk;
    pk.x = (unsigned)f2bf(acc[0]) | ((unsigned)f2bf(acc[1]) << 16);
    pk.y = (unsigned)f2bf(acc[2]) | ((unsigned)f2bf(acc[3]) << 16);
    pk.z = (unsigned)f2bf(acc[4]) | ((unsigned)f2bf(acc[5]) << 16);
    pk.w = (unsigned)f2bf(acc[6]) | ((unsigned)f2bf(acc[7]) << 16);
    *reinterpret_cast<uint4*>(out + boff) = pk;
}

// ---------------- bf16-input MFMA GEMM, 128 rows/block: out = epilogue(X @ W) ----------------
// Each wave owns two 16-row sub-tiles (wave*32, wave*32+16). W split hi/lo.
// MODE 0: z=(acc+b)*s+t, relu ; MODE 1: z=acc*s.  RS: multiply by dis[row]. Output bf16.
template<int KROW, int KPAD, int DOUT, int MODE, int RS>
__global__ __launch_bounds__(256) void gemm_xbf(const unsigned short* __restrict__ X,
                                                const unsigned short* __restrict__ Wh,
                                                const unsigned short* __restrict__ Wl,
                                                const float* __restrict__ b, const float* __restrict__ g,
                                                const float* __restrict__ be, const float* __restrict__ rm,
                                                const float* __restrict__ rv, const int* __restrict__ cnt,
                                                unsigned short* __restrict__ out, int n) {
    constexpr int BN = (DOUT < 128) ? DOUT : 128;
    constexpr int NT = BN / 16;
    constexpr int KSTEPS = KPAD / 32;
    constexpr int LDA = 40;
    __shared__ unsigned short xh[128][LDA];
    __shared__ unsigned short wh[BN][LDA], wl[BN][LDA];

    const int tid = threadIdx.x;
    const int wave = tid >> 6, lane = tid & 63;
    const int row0 = blockIdx.x * 128;
    const int col0 = blockIdx.y * BN;
    const int r_l = lane & 15;
    const int k_l = (lane >> 4) * 8;

    f32x4 acc[2][NT];
#pragma unroll
    for (int m2 = 0; m2 < 2; ++m2)
#pragma unroll
        for (int t = 0; t < NT; ++t) acc[m2][t] = (f32x4){0.f, 0.f, 0.f, 0.f};

    for (int ks = 0; ks < KSTEPS; ++ks) {
        const int k0 = ks * 32;
        // stage X: 128 rows x 32 k (bf16 direct, zero-fill beyond KROW / n)
#pragma unroll
        for (int ii = 0; ii < 2; ++ii) {
            int i = ii * 256 + tid;
            int m = i >> 2, q = i & 3;
            int rr = row0 + m, kk = k0 + q * 8;
            uint4 v = make_uint4(0u, 0u, 0u, 0u);
            if (rr < n && kk < KROW)
                v = *reinterpret_cast<const uint4*>(X + (size_t)rr * KROW + kk);
            *reinterpret_cast<uint4*>(&xh[m][q * 8]) = v;
        }
        // stage W hi/lo tiles
        for (int i = tid; i < BN * 4; i += 256) {
            int cc = i >> 2, q = i & 3;
            size_t goff = (size_t)(col0 + cc) * KPAD + k0 + q * 8;
            *reinterpret_cast<uint4*>(&wh[cc][q * 8]) = *reinterpret_cast<const uint4*>(Wh + goff);
            *reinterpret_cast<uint4*>(&wl[cc][q * 8]) = *reinterpret_cast<const uint4*>(Wl + goff);
        }
        __syncthreads();

        short8v ah0 = *reinterpret_cast<const short8v*>(&xh[wave * 32 + r_l][k_l]);
        short8v ah1 = *reinterpret_cast<const short8v*>(&xh[wave * 32 + 16 + r_l][k_l]);
#pragma unroll
        for (int t = 0; t < NT; ++t) {
            short8v bh = *reinterpret_cast<const short8v*>(&wh[t * 16 + r_l][k_l]);
            short8v bl = *reinterpret_cast<const short8v*>(&wl[t * 16 + r_l][k_l]);
            acc[0][t] = __builtin_amdgcn_mfma_f32_16x16x32_bf16(ah0, bh, acc[0][t], 0, 0, 0);
            acc[0][t] = __builtin_amdgcn_mfma_f32_16x16x32_bf16(ah0, bl, acc[0][t], 0, 0, 0);
            acc[1][t] = __builtin_amdgcn_mfma_f32_16x16x32_bf16(ah1, bh, acc[1][t], 0, 0, 0);
            acc[1][t] = __builtin_amdgcn_mfma_f32_16x16x32_bf16(ah1, bl, acc[1][t], 0, 0, 0);
        }
        __syncthreads();
    }

#pragma unroll
    for (int m2 = 0; m2 < 2; ++m2) {
        const int orow = row0 + wave * 32 + m2 * 16 + (lane >> 4) * 4;
        float dsc[4];
#pragma unroll
        for (int r = 0; r < 4; ++r)
            dsc[r] = (RS && orow + r < n) ? rsqrtf((float)cnt[orow + r] + 1.0f) : 1.0f;

#pragma unroll
        for (int t = 0; t < NT; ++t) {
            int col = col0 + t * 16 + r_l;
            float s, tt, bias;
            if (MODE == 0) {
                float sv = g[col] * rsqrtf(rv[col] + EPS);
                s = sv; tt = be[col] - rm[col] * sv; bias = b[col];
            } else {
                s = g[col] * rsqrtf(rv[col] + EPS); tt = 0.f; bias = 0.f;
            }
#pragma unroll
            for (int r = 0; r < 4; ++r) {
                int rr = orow + r;
                if (rr < n) {
                    float z = acc[m2][t][r];
                    if (MODE == 0) { z = (z + bias) * s + tt; z = fmaxf(z, 0.0f); }
                    else           { z = z * s; }
                    if (RS) z *= dsc[r];
                    out[(size_t)rr * DOUT + col] = f2bf(z);
                }
            }
        }
    }
}

// ---------------- fused classifier (bf16 in): Lin64+ReLU+BN -> Lin32+ReLU+BN -> Lin2 ----------------
__global__ __launch_bounds__(256) void classifier_fused(
    const unsigned short* __restrict__ X,
    const float* __restrict__ cW1, const float* __restrict__ cb1,
    const float* __restrict__ cg1, const float* __restrict__ cbe1,
    const float* __restrict__ crm1, const float* __restrict__ crv1,
    const float* __restrict__ cW2, const float* __restrict__ cb2,
    const float* __restrict__ cg2, const float* __restrict__ cbe2,
    const float* __restrict__ crm2, const float* __restrict__ crv2,
    const float* __restrict__ cW3, const float* __restrict__ cb3,
    float* __restrict__ out, int n)
{
    __shared__ float xs[64][65];
    __shared__ float h1[64][65];
    __shared__ float h2[64][33];
    const int tid = threadIdx.x;
    const int row0 = blockIdx.x * 64;

    for (int i = tid; i < 64 * 8; i += 256) {
        int r = i >> 3, cq = i & 7;
        int rr = row0 + r;
        if (rr < n) {
            short8v v = *reinterpret_cast<const short8v*>(X + (size_t)rr * 64 + cq * 8);
#pragma unroll
            for (int j = 0; j < 8; ++j) xs[r][cq * 8 + j] = bf2f((unsigned short)v[j]);
        } else {
#pragma unroll
            for (int j = 0; j < 8; ++j) xs[r][cq * 8 + j] = 0.0f;
        }
    }
    __syncthreads();

    {   // phase 1: 64 cols x 4 row-groups of 16
        const int col = tid & 63;
        const int rg  = tid >> 6;
        float sv = cg1[col] * rsqrtf(crv1[col] + EPS);
        float tt = cbe1[col] - crm1[col] * sv;
        float bias = cb1[col];
        float accv[16];
#pragma unroll
        for (int r = 0; r < 16; ++r) accv[r] = 0.f;
#pragma unroll 4
        for (int k = 0; k < 64; ++k) {
            float w = cW1[k * 64 + col];
#pragma unroll
            for (int r = 0; r < 16; ++r)
                accv[r] = fmaf(xs[rg * 16 + r][k], w, accv[r]);
        }
#pragma unroll
        for (int r = 0; r < 16; ++r)
            h1[rg * 16 + r][col] = fmaxf(accv[r] + bias, 0.f) * sv + tt;
    }
    __syncthreads();

    {   // phase 2: 32 cols x 8 row-groups of 8
        const int col = tid & 31;
        const int rg  = tid >> 5;
        float sv = cg2[col] * rsqrtf(crv2[col] + EPS);
        float tt = cbe2[col] - crm2[col] * sv;
        float bias = cb2[col];
        float accv[8];
#pragma unroll
        for (int r = 0; r < 8; ++r) accv[r] = 0.f;
#pragma unroll 4
        for (int k = 0; k < 64; ++k) {
            float w = cW2[k * 32 + col];
#pragma unroll
            for (int r = 0; r < 8; ++r)
                accv[r] = fmaf(h1[rg * 8 + r][k], w, accv[r]);
        }
#pragma unroll
        for (int r = 0; r < 8; ++r)
            h2[rg * 8 + r][col] = fmaxf(accv[r] + bias, 0.f) * sv + tt;
    }
    __syncthreads();

    if (tid < 64) {   // phase 3: one row per thread
        int rr = row0 + tid;
        if (rr < n) {
            float a0 = 0.f, a1 = 0.f;
#pragma unroll
            for (int k = 0; k < 32; ++k) {
                float h = h2[tid][k];
                a0 = fmaf(h, cW3[k * 2 + 0], a0);
                a1 = fmaf(h, cW3[k * 2 + 1], a1);
            }
            out[(size_t)rr * 2 + 0] = a0 + cb3[0];
            out[(size_t)rr * 2 + 1] = a1 + cb3[1];
        }
    }
}

// ---------------- launch ----------------

extern "C" void kernel_launch(void* const* d_in, const int* in_sizes, int n_in,
                              void* d_out, int out_size, void* d_ws, size_t ws_size,
                              hipStream_t stream) {
    const float* x  = (const float*)d_in[0];
    const int*   ei = (const int*)d_in[1];
    const int E = in_sizes[1] / 2;
    const int n = in_sizes[0] / 42;
    const int* src = ei;
    const int* dst = ei + E;

    const float *W1 = (const float*)d_in[2],  *b1 = (const float*)d_in[3],  *g1 = (const float*)d_in[4],
                *be1 = (const float*)d_in[5], *rm1 = (const float*)d_in[6], *rv1 = (const float*)d_in[7];
    const float *W2 = (const float*)d_in[8],  *b2 = (const float*)d_in[9],  *g2 = (const float*)d_in[10],
                *be2 = (const float*)d_in[11], *rm2 = (const float*)d_in[12], *rv2 = (const float*)d_in[13];
    const float *W3 = (const float*)d_in[14], *b3 = (const float*)d_in[15], *g3 = (const float*)d_in[16],
                *be3 = (const float*)d_in[17], *rm3 = (const float*)d_in[18], *rv3 = (const float*)d_in[19];
    const float *W4 = (const float*)d_in[20], *b4 = (const float*)d_in[21], *g4 = (const float*)d_in[22],
                *be4 = (const float*)d_in[23], *rm4 = (const float*)d_in[24], *rv4 = (const float*)d_in[25];
    const float *cW1 = (const float*)d_in[26], *cb1 = (const float*)d_in[27], *cg1 = (const float*)d_in[28],
                *cbe1 = (const float*)d_in[29], *crm1 = (const float*)d_in[30], *crv1 = (const float*)d_in[31];
    const float *cW2 = (const float*)d_in[32], *cb2 = (const float*)d_in[33], *cg2 = (const float*)d_in[34],
                *cbe2 = (const float*)d_in[35], *crm2 = (const float*)d_in[36], *crv2 = (const float*)d_in[37];
    const float *cW3 = (const float*)d_in[38], *cb3 = (const float*)d_in[39];

    // ---- workspace layout (all inter-stage tensors bf16) ----
    int* ell = (int*)d_ws;                               // n*64 int (line-aligned rows)
    unsigned short* P   = (unsigned short*)(ell + (size_t)n * CAP);  // n*256 bf16
    unsigned short* Q   = P + (size_t)n * 256;           // n*128 bf16
    unsigned short* R   = Q + (size_t)n * 128;           // n*128 bf16
    unsigned short* xs1 = R + (size_t)n * 128;           // n*48 bf16
    int* cnt = (int*)(xs1 + (size_t)n * 48);             // n int
    unsigned short* w1h = (unsigned short*)(cnt + n);    // 128*64
    unsigned short* w1l = w1h + 128 * 64;
    unsigned short* w2h = w1l + 128 * 64;                // 256*128
    unsigned short* w2l = w2h + 256 * 128;
    unsigned short* w3h = w2l + 256 * 128;               // 128*256
    unsigned short* w3l = w3h + 128 * 256;
    unsigned short* w4h = w3l + 128 * 256;               // 64*128
    unsigned short* w4l = w4h + 64 * 128;

    dim3 blk(256);
    auto nb = [](long total) { return dim3((unsigned)((total + 255) / 256)); };
    const int nbx = (int)(((long)n * 48 + 255) / 256);
    const int nper = (n + NXCD - 1) / NXCD;
    const int nchunk = (E + ECHUNK - 1) / ECHUNK;
    const float* nul = nullptr;

    // ---- ELL build (XCD-filtered, nt loads on streams) + prep ----
    hipMemsetAsync(cnt, 0, (size_t)n * sizeof(int), stream);
    ell_fill<<<dim3(nchunk * NXCD), blk, 0, stream>>>(src, dst, cnt, ell, E, nper);
    prep<<<dim3(nbx + 32 + 128 + 128 + 32), blk, 0, stream>>>(x, cnt, xs1,
                                                              W1, w1h, w1l, W2, w2h, w2l,
                                                              W3, w3h, w3l, W4, w4h, w4l, n, nbx);

    // ---- Layer 1: agg48(xs1)->R ; mfma 48->128 BN+ReLU, row-scale -> Q
    agg_bf<48, 0><<<nb((long)n * 6), blk, 0, stream>>>(xs1, cnt, ell, nul, nul, nul, nul, nul, R, n);
    gemm_xbf<48, 64, 128, 0, 1><<<dim3((n + 127) / 128, 1), blk, 0, stream>>>(R, w1h, w1l, b1, g1, be1, rm1, rv1, cnt, Q, n);

    // ---- Layer 2: agg128(Q)->R ; mfma 128->256 BN+ReLU -> P
    agg_bf<128, 0><<<nb((long)n * 16), blk, 0, stream>>>(Q, cnt, ell, nul, nul, nul, nul, nul, R, n);
    gemm_xbf<128, 128, 256, 0, 0><<<dim3((n + 127) / 128, 2), blk, 0, stream>>>(R, w2h, w2l, b2, g2, be2, rm2, rv2, cnt, P, n);

    // ---- Layer 3: mfma 256->128 (col-scale, row-scale) P->Q ; agg + fused bias/bn/relu -> R
    gemm_xbf<256, 256, 128, 1, 1><<<dim3((n + 127) / 128, 1), blk, 0, stream>>>(P, w3h, w3l, b3, g3, be3, rm3, rv3, cnt, Q, n);
    agg_bf<128, 1><<<nb((long)n * 16), blk, 0, stream>>>(Q, cnt, ell, b3, g3, be3, rm3, rv3, R, n);

    // ---- Layer 4: mfma 128->64 (col-scale, row-scale) R->Q ; agg + fused bias/bn/relu -> R
    gemm_xbf<128, 128, 64, 1, 1><<<dim3((n + 127) / 128, 1), blk, 0, stream>>>(R, w4h, w4l, b4, g4, be4, rm4, rv4, cnt, Q, n);
    agg_bf<64, 1><<<nb((long)n * 8), blk, 0, stream>>>(Q, cnt, ell, b4, g4, be4, rm4, rv4, R, n);

    // ---- Fused classifier (bf16 in)
    classifier_fused<<<dim3((n + 63) / 64), blk, 0, stream>>>(R, cW1, cb1, cg1, cbe1, crm1, crv1,
                                                              cW2, cb2, cg2, cbe2, crm2, crv2,
                                                              cW3, cb3, (float*)d_out, n);
}

// Round 15
// 461.500 us; speedup vs baseline: 1.0230x; 1.0230x over previous
//
#include <hip/hip_runtime.h>

#define EPS 1e-5f
#define CAP 64           // ELL row capacity (Poisson(16) tail @64 ~ 1e-22)
#define NXCD 8
#define ECHUNK 2048      // edges per chunk; 8 blocks (one per XCD) per chunk

typedef __attribute__((ext_vector_type(8))) short short8v;
typedef __attribute__((ext_vector_type(4))) float f32x4;

__device__ __forceinline__ unsigned short f2bf(float f) {
    union { float f; unsigned int u; } v; v.f = f;
    unsigned int r = v.u + 0x7fffu + ((v.u >> 16) & 1u);
    return (unsigned short)(r >> 16);
}
__device__ __forceinline__ float bf2f(unsigned short h) {
    union { unsigned int u; float f; } v; v.u = ((unsigned int)h) << 16;
    return v.f;
}

// ---------------- ELL build: XCD-local by dst-range filter; nt loads for streaming src/dst ----------------
__global__ __launch_bounds__(256) void ell_fill(const int* __restrict__ src, const int* __restrict__ dst,
                                                int* __restrict__ cnt, int* __restrict__ ell,
                                                int E, int nper) {
    const int xcd = blockIdx.x & (NXCD - 1);
    const int chunk = blockIdx.x >> 3;
    const int dLo = xcd * nper;
    const int dHi = dLo + nper;
    const int base = chunk * ECHUNK;
#pragma unroll
    for (int it = 0; it < ECHUNK / 256; ++it) {
        int i = base + it * 256 + threadIdx.x;
        if (i < E) {
            int d = __builtin_nontemporal_load(dst + i);
            if (d >= dLo && d < dHi) {
                int s = __builtin_nontemporal_load(src + i);
                int pos = atomicAdd(&cnt[d], 1);
                if (pos < CAP) ell[((size_t)d << 6) + pos] = s;
            }
        }
    }
}

// ---------------- fused prep: cast_x (42->48, dis-prescale, bf16) + 4x split_w ----------------
__global__ __launch_bounds__(256) void prep(const float* __restrict__ x, const int* __restrict__ cnt,
                                            unsigned short* __restrict__ xs1,
                                            const float* __restrict__ W1, unsigned short* __restrict__ w1h,
                                            unsigned short* __restrict__ w1l,
                                            const float* __restrict__ W2, unsigned short* __restrict__ w2h,
                                            unsigned short* __restrict__ w2l,
                                            const float* __restrict__ W3, unsigned short* __restrict__ w3h,
                                            unsigned short* __restrict__ w3l,
                                            const float* __restrict__ W4, unsigned short* __restrict__ w4h,
                                            unsigned short* __restrict__ w4l,
                                            int n, int nbx) {
    int bi = blockIdx.x;
    if (bi < nbx) {                       // cast_x: xs1 = bf16(dis * x), pad 42->48
        int gid = bi * 256 + threadIdx.x;
        int nd = gid / 48, c = gid - nd * 48;
        if (nd < n) {
            float v = 0.0f;
            if (c < 42) v = x[(size_t)nd * 42 + c] * rsqrtf((float)cnt[nd] + 1.0f);
            xs1[(size_t)nd * 48 + c] = f2bf(v);
        }
        return;
    }
    bi -= nbx;
    if (bi < 32) {                        // split W1: [42][128] -> T hi/lo [128][64] (k-pad 64)
        int i = bi * 256 + threadIdx.x;
        int c = i >> 6, k = i & 63;
        float w = (k < 42) ? W1[(size_t)k * 128 + c] : 0.0f;
        unsigned short h = f2bf(w);
        w1h[i] = h; w1l[i] = f2bf(w - bf2f(h));
        return;
    }
    bi -= 32;
    if (bi < 128) {                       // split W2: [128][256] -> T hi/lo [256][128]
        int i = bi * 256 + threadIdx.x;
        int c = i >> 7, k = i & 127;
        float w = W2[(size_t)k * 256 + c];
        unsigned short h = f2bf(w);
        w2h[i] = h; w2l[i] = f2bf(w - bf2f(h));
        return;
    }
    bi -= 128;
    if (bi < 128) {                       // split W3: [256][128] -> T hi/lo [128][256]
        int i = bi * 256 + threadIdx.x;
        int c = i >> 8, k = i & 255;
        float w = W3[(size_t)k * 128 + c];
        unsigned short h = f2bf(w);
        w3h[i] = h; w3l[i] = f2bf(w - bf2f(h));
        return;
    }
    bi -= 128;
    {                                     // split W4: [128][64] -> T hi/lo [64][128]
        int i = bi * 256 + threadIdx.x;
        int c = i >> 7, k = i & 127;
        float w = W4[(size_t)k * 64 + c];
        unsigned short h = f2bf(w);
        w4h[i] = h; w4l[i] = f2bf(w - bf2f(h));
        return;
    }
}

// ---------------- bf16 prescaled aggregation (ELL): out[nd] = dis[nd]*(x[nd] + sum x[src]) ----------------
// FUSE 0: plain ; FUSE 1: relu(agg + (b*s+t)).  Output bf16. 8 elems (16B) per lane.
template<int D, int FUSE>
__global__ __launch_bounds__(256) void agg_bf(const unsigned short* __restrict__ x,
                                              const int* __restrict__ cnt, const int* __restrict__ ell,
                                              const float* __restrict__ b, const float* __restrict__ g,
                                              const float* __restrict__ be, const float* __restrict__ rm,
                                              const float* __restrict__ rv,
                                              unsigned short* __restrict__ out, int n) {
    constexpr int CPE = D / 8;
    int gid = blockIdx.x * 256 + threadIdx.x;
    int nd = gid / CPE, c = gid - nd * CPE;
    if (nd >= n) return;
    const size_t boff = (size_t)nd * D + c * 8;

    float acc[8];
    {
        short8v v = *reinterpret_cast<const short8v*>(x + boff);
#pragma unroll
        for (int j = 0; j < 8; ++j) acc[j] = bf2f((unsigned short)v[j]);
    }
    const int cv = cnt[nd];
    const int deg = (cv < CAP) ? cv : CAP;
    const float dn = rsqrtf((float)cv + 1.0f);
    const int* row = ell + ((size_t)nd << 6);
    int i = 0;
    for (; i + 2 <= deg; i += 2) {
        int s0 = row[i], s1 = row[i + 1];
        short8v v0 = *reinterpret_cast<const short8v*>(x + (size_t)s0 * D + c * 8);
        short8v v1 = *reinterpret_cast<const short8v*>(x + (size_t)s1 * D + c * 8);
#pragma unroll
        for (int j = 0; j < 8; ++j) acc[j] += bf2f((unsigned short)v0[j]) + bf2f((unsigned short)v1[j]);
    }
    if (i < deg) {
        int s0 = row[i];
        short8v v = *reinterpret_cast<const short8v*>(x + (size_t)s0 * D + c * 8);
#pragma unroll
        for (int j = 0; j < 8; ++j) acc[j] += bf2f((unsigned short)v[j]);
    }

#pragma unroll
    for (int j = 0; j < 8; ++j) acc[j] *= dn;

    if (FUSE == 1) {
#pragma unroll
        for (int j = 0; j < 8; ++j) {
            int col = c * 8 + j;
            float sv = g[col] * rsqrtf(rv[col] + EPS);
            float bb = b[col] * sv + (be[col] - rm[col] * sv);
            acc[j] = fmaxf(acc[j] + bb, 0.0f);
        }
    }

    uint4 pk;
    pk.x = (unsigned)f2bf(acc[0]) | ((unsigned)f2bf(acc[1]) << 16);
    pk.y = (unsigned)f2bf(acc[2]) | ((unsigned)f2bf(acc[3]) << 16);
    pk.z = (unsigned)f2bf(acc[4]) | ((unsigned)f2bf(acc[5]) << 16);
    pk.w = (unsigned)f2bf(acc[6]) | ((unsigned)f2bf(acc[7]) << 16);
    *reinterpret_cast<uint4*>(out + boff) = pk;
}

// ---------------- bf16-input MFMA GEMM: out = epilogue(X @ W), X bf16 [n][KROW], W split hi/lo ----------------
// MODE 0: z=(acc+b)*s+t, relu ; MODE 1: z=acc*s.  RS: multiply by dis[row]. Output bf16.
template<int KROW, int KPAD, int DOUT, int MODE, int RS>
__global__ __launch_bounds__(256) void gemm_xbf(const unsigned short* __restrict__ X,
                                                const unsigned short* __restrict__ Wh,
                                                const unsigned short* __restrict__ Wl,
                                                const float* __restrict__ b, const float* __restrict__ g,
                                                const float* __restrict__ be, const float* __restrict__ rm,
                                                const float* __restrict__ rv, const int* __restrict__ cnt,
                                                unsigned short* __restrict__ out, int n) {
    constexpr int BN = (DOUT < 128) ? DOUT : 128;
    constexpr int NT = BN / 16;
    constexpr int KSTEPS = KPAD / 32;
    constexpr int LDA = 40;
    __shared__ unsigned short xh[64][LDA];
    __shared__ unsigned short wh[BN][LDA], wl[BN][LDA];

    const int tid = threadIdx.x;
    const int wave = tid >> 6, lane = tid & 63;
    const int row0 = blockIdx.x * 64;
    const int col0 = blockIdx.y * BN;
    const int r_l = lane & 15;
    const int k_l = (lane >> 4) * 8;

    f32x4 acc[NT];
#pragma unroll
    for (int t = 0; t < NT; ++t) acc[t] = (f32x4){0.f, 0.f, 0.f, 0.f};

    for (int ks = 0; ks < KSTEPS; ++ks) {
        const int k0 = ks * 32;
        {
            int i = tid;                                  // 64*4 == 256
            int m = i >> 2, q = i & 3;
            int rr = row0 + m, kk = k0 + q * 8;
            uint4 v = make_uint4(0u, 0u, 0u, 0u);
            if (rr < n && kk < KROW)
                v = *reinterpret_cast<const uint4*>(X + (size_t)rr * KROW + kk);
            *reinterpret_cast<uint4*>(&xh[m][q * 8]) = v;
        }
        for (int i = tid; i < BN * 4; i += 256) {
            int cc = i >> 2, q = i & 3;
            size_t goff = (size_t)(col0 + cc) * KPAD + k0 + q * 8;
            *reinterpret_cast<uint4*>(&wh[cc][q * 8]) = *reinterpret_cast<const uint4*>(Wh + goff);
            *reinterpret_cast<uint4*>(&wl[cc][q * 8]) = *reinterpret_cast<const uint4*>(Wl + goff);
        }
        __syncthreads();

        short8v ah = *reinterpret_cast<const short8v*>(&xh[wave * 16 + r_l][k_l]);
#pragma unroll
        for (int t = 0; t < NT; ++t) {
            short8v bh = *reinterpret_cast<const short8v*>(&wh[t * 16 + r_l][k_l]);
            short8v bl = *reinterpret_cast<const short8v*>(&wl[t * 16 + r_l][k_l]);
            acc[t] = __builtin_amdgcn_mfma_f32_16x16x32_bf16(ah, bh, acc[t], 0, 0, 0);
            acc[t] = __builtin_amdgcn_mfma_f32_16x16x32_bf16(ah, bl, acc[t], 0, 0, 0);
        }
        __syncthreads();
    }

    const int orow = row0 + wave * 16 + (lane >> 4) * 4;
    float dsc[4];
#pragma unroll
    for (int r = 0; r < 4; ++r)
        dsc[r] = (RS && orow + r < n) ? rsqrtf((float)cnt[orow + r] + 1.0f) : 1.0f;

#pragma unroll
    for (int t = 0; t < NT; ++t) {
        int col = col0 + t * 16 + r_l;
        float s, tt, bias;
        if (MODE == 0) {
            float sv = g[col] * rsqrtf(rv[col] + EPS);
            s = sv; tt = be[col] - rm[col] * sv; bias = b[col];
        } else {
            s = g[col] * rsqrtf(rv[col] + EPS); tt = 0.f; bias = 0.f;
        }
#pragma unroll
        for (int r = 0; r < 4; ++r) {
            int rr = orow + r;
            if (rr < n) {
                float z = acc[t][r];
                if (MODE == 0) { z = (z + bias) * s + tt; z = fmaxf(z, 0.0f); }
                else           { z = z * s; }
                if (RS) z *= dsc[r];
                out[(size_t)rr * DOUT + col] = f2bf(z);
            }
        }
    }
}

// ---------------- fused classifier (bf16 in): Lin64+ReLU+BN -> Lin32+ReLU+BN -> Lin2 ----------------
__global__ __launch_bounds__(256) void classifier_fused(
    const unsigned short* __restrict__ X,
    const float* __restrict__ cW1, const float* __restrict__ cb1,
    const float* __restrict__ cg1, const float* __restrict__ cbe1,
    const float* __restrict__ crm1, const float* __restrict__ crv1,
    const float* __restrict__ cW2, const float* __restrict__ cb2,
    const float* __restrict__ cg2, const float* __restrict__ cbe2,
    const float* __restrict__ crm2, const float* __restrict__ crv2,
    const float* __restrict__ cW3, const float* __restrict__ cb3,
    float* __restrict__ out, int n)
{
    __shared__ float xs[64][65];
    __shared__ float h1[64][65];
    __shared__ float h2[64][33];
    const int tid = threadIdx.x;
    const int row0 = blockIdx.x * 64;

    for (int i = tid; i < 64 * 8; i += 256) {
        int r = i >> 3, cq = i & 7;
        int rr = row0 + r;
        if (rr < n) {
            short8v v = *reinterpret_cast<const short8v*>(X + (size_t)rr * 64 + cq * 8);
#pragma unroll
            for (int j = 0; j < 8; ++j) xs[r][cq * 8 + j] = bf2f((unsigned short)v[j]);
        } else {
#pragma unroll
            for (int j = 0; j < 8; ++j) xs[r][cq * 8 + j] = 0.0f;
        }
    }
    __syncthreads();

    {   // phase 1: 64 cols x 4 row-groups of 16
        const int col = tid & 63;
        const int rg  = tid >> 6;
        float sv = cg1[col] * rsqrtf(crv1[col] + EPS);
        float tt = cbe1[col] - crm1[col] * sv;
        float bias = cb1[col];
        float accv[16];
#pragma unroll
        for (int r = 0; r < 16; ++r) accv[r] = 0.f;
#pragma unroll 4
        for (int k = 0; k < 64; ++k) {
            float w = cW1[k * 64 + col];
#pragma unroll
            for (int r = 0; r < 16; ++r)
                accv[r] = fmaf(xs[rg * 16 + r][k], w, accv[r]);
        }
#pragma unroll
        for (int r = 0; r < 16; ++r)
            h1[rg * 16 + r][col] = fmaxf(accv[r] + bias, 0.f) * sv + tt;
    }
    __syncthreads();

    {   // phase 2: 32 cols x 8 row-groups of 8
        const int col = tid & 31;
        const int rg  = tid >> 5;
        float sv = cg2[col] * rsqrtf(crv2[col] + EPS);
        float tt = cbe2[col] - crm2[col] * sv;
        float bias = cb2[col];
        float accv[8];
#pragma unroll
        for (int r = 0; r < 8; ++r) accv[r] = 0.f;
#pragma unroll 4
        for (int k = 0; k < 64; ++k) {
            float w = cW2[k * 32 + col];
#pragma unroll
            for (int r = 0; r < 8; ++r)
                accv[r] = fmaf(h1[rg * 8 + r][k], w, accv[r]);
        }
#pragma unroll
        for (int r = 0; r < 8; ++r)
            h2[rg * 8 + r][col] = fmaxf(accv[r] + bias, 0.f) * sv + tt;
    }
    __syncthreads();

    if (tid < 64) {   // phase 3: one row per thread
        int rr = row0 + tid;
        if (rr < n) {
            float a0 = 0.f, a1 = 0.f;
#pragma unroll
            for (int k = 0; k < 32; ++k) {
                float h = h2[tid][k];
                a0 = fmaf(h, cW3[k * 2 + 0], a0);
                a1 = fmaf(h, cW3[k * 2 + 1], a1);
            }
            out[(size_t)rr * 2 + 0] = a0 + cb3[0];
            out[(size_t)rr * 2 + 1] = a1 + cb3[1];
        }
    }
}

// ---------------- launch ----------------

extern "C" void kernel_launch(void* const* d_in, const int* in_sizes, int n_in,
                              void* d_out, int out_size, void* d_ws, size_t ws_size,
                              hipStream_t stream) {
    const float* x  = (const float*)d_in[0];
    const int*   ei = (const int*)d_in[1];
    const int E = in_sizes[1] / 2;
    const int n = in_sizes[0] / 42;
    const int* src = ei;
    const int* dst = ei + E;

    const float *W1 = (const float*)d_in[2],  *b1 = (const float*)d_in[3],  *g1 = (const float*)d_in[4],
                *be1 = (const float*)d_in[5], *rm1 = (const float*)d_in[6], *rv1 = (const float*)d_in[7];
    const float *W2 = (const float*)d_in[8],  *b2 = (const float*)d_in[9],  *g2 = (const float*)d_in[10],
                *be2 = (const float*)d_in[11], *rm2 = (const float*)d_in[12], *rv2 = (const float*)d_in[13];
    const float *W3 = (const float*)d_in[14], *b3 = (const float*)d_in[15], *g3 = (const float*)d_in[16],
                *be3 = (const float*)d_in[17], *rm3 = (const float*)d_in[18], *rv3 = (const float*)d_in[19];
    const float *W4 = (const float*)d_in[20], *b4 = (const float*)d_in[21], *g4 = (const float*)d_in[22],
                *be4 = (const float*)d_in[23], *rm4 = (const float*)d_in[24], *rv4 = (const float*)d_in[25];
    const float *cW1 = (const float*)d_in[26], *cb1 = (const float*)d_in[27], *cg1 = (const float*)d_in[28],
                *cbe1 = (const float*)d_in[29], *crm1 = (const float*)d_in[30], *crv1 = (const float*)d_in[31];
    const float *cW2 = (const float*)d_in[32], *cb2 = (const float*)d_in[33], *cg2 = (const float*)d_in[34],
                *cbe2 = (const float*)d_in[35], *crm2 = (const float*)d_in[36], *crv2 = (const float*)d_in[37];
    const float *cW3 = (const float*)d_in[38], *cb3 = (const float*)d_in[39];

    // ---- workspace layout (all inter-stage tensors bf16) ----
    int* ell = (int*)d_ws;                               // n*64 int (line-aligned rows)
    unsigned short* P   = (unsigned short*)(ell + (size_t)n * CAP);  // n*256 bf16
    unsigned short* Q   = P + (size_t)n * 256;           // n*128 bf16
    unsigned short* R   = Q + (size_t)n * 128;           // n*128 bf16
    unsigned short* xs1 = R + (size_t)n * 128;           // n*48 bf16
    int* cnt = (int*)(xs1 + (size_t)n * 48);             // n int
    unsigned short* w1h = (unsigned short*)(cnt + n);    // 128*64
    unsigned short* w1l = w1h + 128 * 64;
    unsigned short* w2h = w1l + 128 * 64;                // 256*128
    unsigned short* w2l = w2h + 256 * 128;
    unsigned short* w3h = w2l + 256 * 128;               // 128*256
    unsigned short* w3l = w3h + 128 * 256;
    unsigned short* w4h = w3l + 128 * 256;               // 64*128
    unsigned short* w4l = w4h + 64 * 128;

    dim3 blk(256);
    auto nb = [](long total) { return dim3((unsigned)((total + 255) / 256)); };
    const int nbx = (int)(((long)n * 48 + 255) / 256);
    const int nper = (n + NXCD - 1) / NXCD;
    const int nchunk = (E + ECHUNK - 1) / ECHUNK;
    const float* nul = nullptr;

    // ---- ELL build (XCD-filtered, nt loads on streams) + prep ----
    hipMemsetAsync(cnt, 0, (size_t)n * sizeof(int), stream);
    ell_fill<<<dim3(nchunk * NXCD), blk, 0, stream>>>(src, dst, cnt, ell, E, nper);
    prep<<<dim3(nbx + 32 + 128 + 128 + 32), blk, 0, stream>>>(x, cnt, xs1,
                                                              W1, w1h, w1l, W2, w2h, w2l,
                                                              W3, w3h, w3l, W4, w4h, w4l, n, nbx);

    // ---- Layer 1: agg48(xs1)->R ; mfma 48->128 BN+ReLU, row-scale -> Q
    agg_bf<48, 0><<<nb((long)n * 6), blk, 0, stream>>>(xs1, cnt, ell, nul, nul, nul, nul, nul, R, n);
    gemm_xbf<48, 64, 128, 0, 1><<<dim3((n + 63) / 64, 1), blk, 0, stream>>>(R, w1h, w1l, b1, g1, be1, rm1, rv1, cnt, Q, n);

    // ---- Layer 2: agg128(Q)->R ; mfma 128->256 BN+ReLU -> P
    agg_bf<128, 0><<<nb((long)n * 16), blk, 0, stream>>>(Q, cnt, ell, nul, nul, nul, nul, nul, R, n);
    gemm_xbf<128, 128, 256, 0, 0><<<dim3((n + 63) / 64, 2), blk, 0, stream>>>(R, w2h, w2l, b2, g2, be2, rm2, rv2, cnt, P, n);

    // ---- Layer 3: mfma 256->128 (col-scale, row-scale) P->Q ; agg + fused bias/bn/relu -> R
    gemm_xbf<256, 256, 128, 1, 1><<<dim3((n + 63) / 64, 1), blk, 0, stream>>>(P, w3h, w3l, b3, g3, be3, rm3, rv3, cnt, Q, n);
    agg_bf<128, 1><<<nb((long)n * 16), blk, 0, stream>>>(Q, cnt, ell, b3, g3, be3, rm3, rv3, R, n);

    // ---- Layer 4: mfma 128->64 (col-scale, row-scale) R->Q ; agg + fused bias/bn/relu -> R
    gemm_xbf<128, 128, 64, 1, 1><<<dim3((n + 63) / 64, 1), blk, 0, stream>>>(R, w4h, w4l, b4, g4, be4, rm4, rv4, cnt, Q, n);
    agg_bf<64, 1><<<nb((long)n * 8), blk, 0, stream>>>(Q, cnt, ell, b4, g4, be4, rm4, rv4, R, n);

    // ---- Fused classifier (bf16 in)
    classifier_fused<<<dim3((n + 63) / 64), blk, 0, stream>>>(R, cW1, cb1, cg1, cbe1, crm1, crv1,
                                                              cW2, cb2, cg2, cbe2, crm2, crv2,
                                                              cW3, cb3, (float*)d_out, n);
}